// Round 2
// baseline (650.554 us; speedup 1.0000x reference)
//
#include <hip/hip_runtime.h>
#include <math.h>

#define BB 32
#define SS 2048
#define HH 1024
#define AA 256
#define NEGV (-1e20f)

// ---------------- K1: c[b,a] = bias[a] + dot(h_t[b,:], W[a, H:2H]) ----------
__global__ __launch_bounds__(256) void k1_ctx(const float* __restrict__ h_t,
                                              const float* __restrict__ W,
                                              const float* __restrict__ bias,
                                              float* __restrict__ c) {
    int wave = threadIdx.x >> 6;
    int lane = threadIdx.x & 63;
    int pair = blockIdx.x * 4 + wave;          // (b,a) flat index, < B*A
    if (pair >= BB * AA) return;
    int b = pair >> 8;                          // /A
    int a = pair & (AA - 1);
    const float* ht = h_t + (size_t)b * HH;
    const float* w2 = W + (size_t)a * 2 * HH + HH;
    float acc = 0.f;
    for (int k = lane; k < HH; k += 64)
        acc += ht[k] * w2[k];
    for (int off = 32; off; off >>= 1)
        acc += __shfl_down(acc, off, 64);
    if (lane == 0) c[pair] = acc + bias[a];
}

// ---------------- K2: y[row] = sum_a tanh(h_i[row,:]·W1[a,:] + c[b,a])*u[a] -
#define BM 64
#define KT 16
__global__ __launch_bounds__(256) void k2_scores(const float* __restrict__ h_i,
                                                 const float* __restrict__ W,
                                                 const float* __restrict__ c,
                                                 const float* __restrict__ u,
                                                 float* __restrict__ y) {
    __shared__ float As[BM][KT + 1];   // 64 x 17
    __shared__ float Bs[KT][AA + 1];   // 16 x 257  (Bs[kk][a])
    __shared__ float red[BM][16];

    const int tid = threadIdx.x;
    const int tx = tid & 15;           // col group: cols tx + 16*j
    const int ty = tid >> 4;           // row group: rows ty*4 + r
    const int r0 = blockIdx.x * BM;    // global row base (row = b*S + s)
    const int batch = r0 / SS;         // BM divides S, so whole block same b

    float acc[4][16];
#pragma unroll
    for (int r = 0; r < 4; ++r)
#pragma unroll
        for (int j = 0; j < 16; ++j) acc[r][j] = 0.f;

    for (int k0 = 0; k0 < HH; k0 += KT) {
        // stage A tile: 64 rows x 16 k
        {
            int row = tid >> 2;
            int kc = (tid & 3) * 4;
            float4 v = *reinterpret_cast<const float4*>(
                &h_i[(size_t)(r0 + row) * HH + k0 + kc]);
            As[row][kc + 0] = v.x; As[row][kc + 1] = v.y;
            As[row][kc + 2] = v.z; As[row][kc + 3] = v.w;
        }
        // stage B tile (transposed): 256 a x 16 k -> Bs[kk][a]
#pragma unroll
        for (int j = 0; j < 4; ++j) {
            int f = j * 256 + tid;          // 0..1023
            int a = f >> 2;
            int kq = (f & 3) * 4;
            float4 v = *reinterpret_cast<const float4*>(
                &W[(size_t)a * 2 * HH + k0 + kq]);
            Bs[kq + 0][a] = v.x; Bs[kq + 1][a] = v.y;
            Bs[kq + 2][a] = v.z; Bs[kq + 3][a] = v.w;
        }
        __syncthreads();
#pragma unroll
        for (int kk = 0; kk < KT; ++kk) {
            float af[4], bf[16];
#pragma unroll
            for (int r = 0; r < 4; ++r) af[r] = As[ty * 4 + r][kk];
#pragma unroll
            for (int j = 0; j < 16; ++j) bf[j] = Bs[kk][tx + 16 * j];
#pragma unroll
            for (int r = 0; r < 4; ++r)
#pragma unroll
                for (int j = 0; j < 16; ++j) acc[r][j] += af[r] * bf[j];
        }
        __syncthreads();
    }

    // epilogue: tanh, *u, reduce over the 256 columns
#pragma unroll
    for (int r = 0; r < 4; ++r) {
        float part = 0.f;
#pragma unroll
        for (int j = 0; j < 16; ++j) {
            int col = tx + 16 * j;
            float z = acc[r][j] + c[batch * AA + col];
            part += tanhf(z) * u[col];
        }
        red[ty * 4 + r][tx] = part;
    }
    __syncthreads();
    if (tid < BM) {
        float s = 0.f;
#pragma unroll
        for (int j = 0; j < 16; ++j) s += red[tid][j];
        y[r0 + tid] = s;
    }
}

// ---------------- K3: cross-batch scatter + mask + row softmax --------------
__global__ __launch_bounds__(256) void k3_softmax(const float* __restrict__ y,
                                                  const int* __restrict__ mask,
                                                  float* __restrict__ alpha) {
    const int b = blockIdx.x;
    const int tid = threadIdx.x;
    float beta[8];
    float mx = -INFINITY;
#pragma unroll
    for (int i = 0; i < 8; ++i) {
        int s = tid + i * 256;
        int cnt = 0;
        for (int bb = 0; bb <= b; ++bb) cnt += (mask[bb * SS + s] != 0);
        int p = cnt - 1; if (p < 0) p = 0;
        float v = (mask[b * SS + s] != 0) ? y[p * SS + s] : NEGV;
        beta[i] = v;
        mx = fmaxf(mx, v);
    }
    __shared__ float sm[4], ssum[4];
    for (int off = 32; off; off >>= 1) mx = fmaxf(mx, __shfl_xor(mx, off, 64));
    if ((tid & 63) == 0) sm[tid >> 6] = mx;
    __syncthreads();
    mx = fmaxf(fmaxf(sm[0], sm[1]), fmaxf(sm[2], sm[3]));

    float e[8];
    float sum = 0.f;
#pragma unroll
    for (int i = 0; i < 8; ++i) { e[i] = expf(beta[i] - mx); sum += e[i]; }
    for (int off = 32; off; off >>= 1) sum += __shfl_xor(sum, off, 64);
    if ((tid & 63) == 0) ssum[tid >> 6] = sum;
    __syncthreads();
    sum = ssum[0] + ssum[1] + ssum[2] + ssum[3];
    float inv = 1.f / sum;
#pragma unroll
    for (int i = 0; i < 8; ++i) alpha[b * SS + tid + i * 256] = e[i] * inv;
}

// ---------------- K4a: partial[b,ch,h] = sum_{s in chunk} alpha*h_i ---------
#define CH 16
#define SCH (SS / CH)  // 128
__global__ __launch_bounds__(256) void k4a_partial(const float* __restrict__ h_i,
                                                   const float* __restrict__ alpha,
                                                   float* __restrict__ partial) {
    const int b = blockIdx.x >> 4;
    const int ch = blockIdx.x & (CH - 1);
    const int tid = threadIdx.x;
    const float* base = h_i + (size_t)b * SS * HH + (size_t)ch * SCH * HH;
    const float* al = alpha + b * SS + ch * SCH;
    float4 acc = {0.f, 0.f, 0.f, 0.f};
    for (int s = 0; s < SCH; ++s) {
        float a = al[s];
        float4 v = *reinterpret_cast<const float4*>(&base[(size_t)s * HH + tid * 4]);
        acc.x += a * v.x; acc.y += a * v.y; acc.z += a * v.z; acc.w += a * v.w;
    }
    *reinterpret_cast<float4*>(&partial[((size_t)(b * CH + ch)) * HH + tid * 4]) = acc;
}

// ---------------- K4b: out[b,h] = sum_ch partial[b,ch,h] --------------------
__global__ __launch_bounds__(256) void k4b_reduce(const float* __restrict__ partial,
                                                  float* __restrict__ out) {
    int i = blockIdx.x * 256 + threadIdx.x;   // 0..32767
    int b = i >> 10, h = i & (HH - 1);
    float s = 0.f;
#pragma unroll
    for (int ch = 0; ch < CH; ++ch)
        s += partial[((size_t)(b * CH + ch)) * HH + h];
    out[i] = s;
}

extern "C" void kernel_launch(void* const* d_in, const int* in_sizes, int n_in,
                              void* d_out, int out_size, void* d_ws, size_t ws_size,
                              hipStream_t stream) {
    const float* h_i  = (const float*)d_in[0];
    const float* h_t  = (const float*)d_in[1];
    const int*   mask = (const int*)d_in[2];
    const float* W    = (const float*)d_in[3];
    const float* bias = (const float*)d_in[4];
    const float* u    = (const float*)d_in[5];
    float* out = (float*)d_out;

    float* c       = (float*)d_ws;                 // B*A      = 8192
    float* y       = c + BB * AA;                  // B*S      = 65536
    float* alpha   = y + BB * SS;                  // B*S      = 65536
    float* partial = alpha + BB * SS;              // B*CH*H   = 524288

    k1_ctx<<<(BB * AA) / 4, 256, 0, stream>>>(h_t, W, bias, c);
    k2_scores<<<(BB * SS) / BM, 256, 0, stream>>>(h_i, W, c, u, y);
    k3_softmax<<<BB, 256, 0, stream>>>(y, mask, alpha);
    k4a_partial<<<BB * CH, 256, 0, stream>>>(h_i, alpha, partial);
    k4b_reduce<<<(BB * HH) / 256, 256, 0, stream>>>(partial, out);
}

// Round 3
// 174.604 us; speedup vs baseline: 3.7259x; 3.7259x over previous
//
#include <hip/hip_runtime.h>
#include <math.h>

#define BB 32
#define SS 2048
#define HH 1024
#define AA 256
#define NEGV (-1e20f)

typedef _Float16 half8 __attribute__((ext_vector_type(8)));
typedef float f32x4 __attribute__((ext_vector_type(4)));

__device__ inline void async_lds16(const void* g, void* l) {
    __builtin_amdgcn_global_load_lds(
        (const __attribute__((address_space(1))) unsigned int*)g,
        (__attribute__((address_space(3))) unsigned int*)l, 16, 0, 0);
}

// ---------------- K0: cast W1 (first H cols of W) to f16 --------------------
__global__ __launch_bounds__(256) void k0_w16(const float* __restrict__ W,
                                              _Float16* __restrict__ W16) {
    int idx = blockIdx.x * 256 + threadIdx.x;     // < A*H = 262144
    int a = idx >> 10;
    int k = idx & (HH - 1);
    W16[idx] = (_Float16)W[(size_t)a * 2 * HH + k];
}

// ---------------- K1: c[b,a] = bias[a] + dot(h_t[b,:], W[a, H:2H]) ----------
__global__ __launch_bounds__(256) void k1_ctx(const float* __restrict__ h_t,
                                              const float* __restrict__ W,
                                              const float* __restrict__ bias,
                                              float* __restrict__ c) {
    int wave = threadIdx.x >> 6;
    int lane = threadIdx.x & 63;
    int pair = blockIdx.x * 4 + wave;
    if (pair >= BB * AA) return;
    int b = pair >> 8;
    int a = pair & (AA - 1);
    const float* ht = h_t + (size_t)b * HH;
    const float* w2 = W + (size_t)a * 2 * HH + HH;
    float acc = 0.f;
    for (int k = lane; k < HH; k += 64)
        acc += ht[k] * w2[k];
    for (int off = 32; off; off >>= 1)
        acc += __shfl_down(acc, off, 64);
    if (lane == 0) c[pair] = acc + bias[a];
}

// ---------------- K2: MFMA f16 score GEMM + tanh*u reduce -------------------
// block: 256 rows x 256 cols, 512 threads (8 waves, 4x2), BK=32
__global__ __launch_bounds__(512, 2) void k2_mfma(const float* __restrict__ h_i,
                                                  const _Float16* __restrict__ W16,
                                                  const float* __restrict__ c,
                                                  const float* __restrict__ u,
                                                  float* __restrict__ y) {
    __shared__ _Float16 Alds[4][256][8];   // [kslot][row][8 f16] 16 KB
    __shared__ _Float16 Blds[4][256][8];   // [kslot][col][8 f16] 16 KB
    __shared__ float c_s[AA], u_s[AA];
    __shared__ float red[2][256];

    const int tid = threadIdx.x;
    const int lane = tid & 63;
    const int wave = tid >> 6;
    const int wr = wave >> 1;              // 0..3 -> row slab of 64
    const int wc = wave & 1;               // 0..1 -> col slab of 128
    const int r0 = blockIdx.x * 256;
    const int batch = r0 / SS;

    if (tid < AA) { c_s[tid] = c[batch * AA + tid]; u_s[tid] = u[tid]; }

    f32x4 acc[4][8];
#pragma unroll
    for (int rf = 0; rf < 4; ++rf)
#pragma unroll
        for (int cf = 0; cf < 8; ++cf) acc[rf][cf] = (f32x4){0.f, 0.f, 0.f, 0.f};

    // A staging: thread handles rows (tid>>2) and (tid>>2)+128, kslot tid&3
    const int arow = tid >> 2;
    const int akslot = tid & 3;
    const float* Abase = h_i + (size_t)(r0 + arow) * HH + akslot * 8;

    // B staging slot bases (wave-uniform)
    const int bslot0 = __builtin_amdgcn_readfirstlane(wave * 64);
    const int bslot1 = __builtin_amdgcn_readfirstlane(512 + wave * 64);
    _Float16* Bflat = &Blds[0][0][0];

    const int kq = lane >> 4;              // 0..3
    const int lr = lane & 15;

    for (int k0 = 0; k0 < HH; k0 += 32) {
        // ---- B tile: async global->LDS (already f16), 2 slots/lane
        {
            int sl = bslot0 + lane;
            int col = sl & 255, ks = sl >> 8;
            async_lds16(W16 + (size_t)col * HH + k0 + ks * 8, Bflat + (size_t)bslot0 * 8);
            sl = bslot1 + lane;
            col = sl & 255; ks = sl >> 8;
            async_lds16(W16 + (size_t)col * HH + k0 + ks * 8, Bflat + (size_t)bslot1 * 8);
        }
        // ---- A tile: load f32, convert, ds_write
        {
            float4 v0 = *reinterpret_cast<const float4*>(Abase + k0);
            float4 v1 = *reinterpret_cast<const float4*>(Abase + k0 + 4);
            half8 h;
            h[0] = (_Float16)v0.x; h[1] = (_Float16)v0.y;
            h[2] = (_Float16)v0.z; h[3] = (_Float16)v0.w;
            h[4] = (_Float16)v1.x; h[5] = (_Float16)v1.y;
            h[6] = (_Float16)v1.z; h[7] = (_Float16)v1.w;
            *reinterpret_cast<half8*>(&Alds[akslot][arow][0]) = h;
            float4 w0 = *reinterpret_cast<const float4*>(Abase + (size_t)128 * HH + k0);
            float4 w1 = *reinterpret_cast<const float4*>(Abase + (size_t)128 * HH + k0 + 4);
            h[0] = (_Float16)w0.x; h[1] = (_Float16)w0.y;
            h[2] = (_Float16)w0.z; h[3] = (_Float16)w0.w;
            h[4] = (_Float16)w1.x; h[5] = (_Float16)w1.y;
            h[6] = (_Float16)w1.z; h[7] = (_Float16)w1.w;
            *reinterpret_cast<half8*>(&Alds[akslot][arow + 128][0]) = h;
        }
        __syncthreads();

        half8 af[4], bf[8];
#pragma unroll
        for (int rf = 0; rf < 4; ++rf)
            af[rf] = *reinterpret_cast<half8*>(&Alds[kq][wr * 64 + rf * 16 + lr][0]);
#pragma unroll
        for (int cf = 0; cf < 8; ++cf)
            bf[cf] = *reinterpret_cast<half8*>(&Blds[kq][wc * 128 + cf * 16 + lr][0]);
#pragma unroll
        for (int rf = 0; rf < 4; ++rf)
#pragma unroll
            for (int cf = 0; cf < 8; ++cf)
                acc[rf][cf] = __builtin_amdgcn_mfma_f32_16x16x32_f16(
                    af[rf], bf[cf], acc[rf][cf], 0, 0, 0);
        __syncthreads();
    }

    // ---- epilogue: z += c[a]; sum_a tanh(z)*u[a]
#pragma unroll
    for (int rf = 0; rf < 4; ++rf) {
#pragma unroll
        for (int j = 0; j < 4; ++j) {
            float v = 0.f;
#pragma unroll
            for (int cf = 0; cf < 8; ++cf) {
                int col = wc * 128 + cf * 16 + lr;
                float z = acc[rf][cf][j] + c_s[col];
                v += tanhf(z) * u_s[col];
            }
            v += __shfl_xor(v, 1, 64);
            v += __shfl_xor(v, 2, 64);
            v += __shfl_xor(v, 4, 64);
            v += __shfl_xor(v, 8, 64);
            if (lr == 0) red[wc][wr * 64 + rf * 16 + kq * 4 + j] = v;
        }
    }
    __syncthreads();
    if (tid < 256) y[r0 + tid] = red[0][tid] + red[1][tid];
}

// ---------------- K3: cross-batch scatter + mask + row softmax --------------
__global__ __launch_bounds__(256) void k3_softmax(const float* __restrict__ y,
                                                  const int* __restrict__ mask,
                                                  float* __restrict__ alpha) {
    const int b = blockIdx.x;
    const int tid = threadIdx.x;
    float beta[8];
    float mx = -INFINITY;
#pragma unroll
    for (int i = 0; i < 8; ++i) {
        int s = tid + i * 256;
        int cnt = 0;
        for (int bb = 0; bb <= b; ++bb) cnt += (mask[bb * SS + s] != 0);
        int p = cnt - 1; if (p < 0) p = 0;
        float v = (mask[b * SS + s] != 0) ? y[p * SS + s] : NEGV;
        beta[i] = v;
        mx = fmaxf(mx, v);
    }
    __shared__ float sm[4], ssum[4];
    for (int off = 32; off; off >>= 1) mx = fmaxf(mx, __shfl_xor(mx, off, 64));
    if ((tid & 63) == 0) sm[tid >> 6] = mx;
    __syncthreads();
    mx = fmaxf(fmaxf(sm[0], sm[1]), fmaxf(sm[2], sm[3]));

    float e[8];
    float sum = 0.f;
#pragma unroll
    for (int i = 0; i < 8; ++i) { e[i] = expf(beta[i] - mx); sum += e[i]; }
    for (int off = 32; off; off >>= 1) sum += __shfl_xor(sum, off, 64);
    if ((tid & 63) == 0) ssum[tid >> 6] = sum;
    __syncthreads();
    sum = ssum[0] + ssum[1] + ssum[2] + ssum[3];
    float inv = 1.f / sum;
#pragma unroll
    for (int i = 0; i < 8; ++i) alpha[b * SS + tid + i * 256] = e[i] * inv;
}

// ---------------- K4a: partial[b,ch,h] = sum_{s in chunk} alpha*h_i ---------
#define CH 8
#define SCH (SS / CH)  // 256
__global__ __launch_bounds__(256) void k4a_partial(const float* __restrict__ h_i,
                                                   const float* __restrict__ alpha,
                                                   float* __restrict__ partial) {
    const int b = blockIdx.x >> 3;
    const int ch = blockIdx.x & (CH - 1);
    const int tid = threadIdx.x;
    const float* base = h_i + (size_t)b * SS * HH + (size_t)ch * SCH * HH;
    const float* al = alpha + b * SS + ch * SCH;
    float4 acc = {0.f, 0.f, 0.f, 0.f};
    for (int s = 0; s < SCH; ++s) {
        float a = al[s];
        float4 v = *reinterpret_cast<const float4*>(&base[(size_t)s * HH + tid * 4]);
        acc.x += a * v.x; acc.y += a * v.y; acc.z += a * v.z; acc.w += a * v.w;
    }
    *reinterpret_cast<float4*>(&partial[((size_t)(b * CH + ch)) * HH + tid * 4]) = acc;
}

// ---------------- K4b: out[b,h] = sum_ch partial[b,ch,h] --------------------
__global__ __launch_bounds__(256) void k4b_reduce(const float* __restrict__ partial,
                                                  float* __restrict__ out) {
    int i = blockIdx.x * 256 + threadIdx.x;   // 0..32767
    int b = i >> 10, h = i & (HH - 1);
    float s = 0.f;
#pragma unroll
    for (int ch = 0; ch < CH; ++ch)
        s += partial[((size_t)(b * CH + ch)) * HH + h];
    out[i] = s;
}

extern "C" void kernel_launch(void* const* d_in, const int* in_sizes, int n_in,
                              void* d_out, int out_size, void* d_ws, size_t ws_size,
                              hipStream_t stream) {
    const float* h_i  = (const float*)d_in[0];
    const float* h_t  = (const float*)d_in[1];
    const int*   mask = (const int*)d_in[2];
    const float* W    = (const float*)d_in[3];
    const float* bias = (const float*)d_in[4];
    const float* u    = (const float*)d_in[5];
    float* out = (float*)d_out;

    float* c       = (float*)d_ws;                 // 8192
    float* y       = c + BB * AA;                  // 65536
    float* alpha   = y + BB * SS;                  // 65536
    float* partial = alpha + BB * SS;              // B*CH*H = 262144
    _Float16* W16  = (_Float16*)(partial + BB * CH * HH);  // 262144 f16

    k0_w16<<<(AA * HH) / 256, 256, 0, stream>>>(W, W16);
    k1_ctx<<<(BB * AA) / 4, 256, 0, stream>>>(h_t, W, bias, c);
    k2_mfma<<<(BB * SS) / 256, 512, 0, stream>>>(h_i, W16, c, u, y);
    k3_softmax<<<BB, 256, 0, stream>>>(y, mask, alpha);
    k4a_partial<<<BB * CH, 256, 0, stream>>>(h_i, alpha, partial);
    k4b_reduce<<<(BB * HH) / 256, 256, 0, stream>>>(partial, out);
}

// Round 5
// 160.084 us; speedup vs baseline: 4.0638x; 1.0907x over previous
//
#include <hip/hip_runtime.h>
#include <math.h>

#define BB 32
#define SS 2048
#define HH 1024
#define AA 256
#define NEGV (-1e20f)
#define BK 32

typedef _Float16 half8 __attribute__((ext_vector_type(8)));
typedef float f32x4 __attribute__((ext_vector_type(4)));

__device__ inline void async_lds16(const void* g, void* l) {
    __builtin_amdgcn_global_load_lds(
        (const __attribute__((address_space(1))) unsigned int*)g,
        (__attribute__((address_space(3))) unsigned int*)l, 16, 0, 0);
}

// ---------------- K0: cast W1 (first H cols of W) to f16 --------------------
__global__ __launch_bounds__(256) void k0_w16(const float* __restrict__ W,
                                              _Float16* __restrict__ W16) {
    int idx = blockIdx.x * 256 + threadIdx.x;     // < A*H = 262144
    int a = idx >> 10;
    int k = idx & (HH - 1);
    W16[idx] = (_Float16)W[(size_t)a * 2 * HH + k];
}

// ---------------- K1: c[b,a] = bias[a] + dot(h_t[b,:], W[a, H:2H]) ----------
__global__ __launch_bounds__(256) void k1_ctx(const float* __restrict__ h_t,
                                              const float* __restrict__ W,
                                              const float* __restrict__ bias,
                                              float* __restrict__ c) {
    int wave = threadIdx.x >> 6;
    int lane = threadIdx.x & 63;
    int pair = blockIdx.x * 4 + wave;
    if (pair >= BB * AA) return;
    int b = pair >> 8;
    int a = pair & (AA - 1);
    const float* ht = h_t + (size_t)b * HH;
    const float* w2 = W + (size_t)a * 2 * HH + HH;
    float acc = 0.f;
    for (int k = lane; k < HH; k += 64)
        acc += ht[k] * w2[k];
    for (int off = 32; off; off >>= 1)
        acc += __shfl_down(acc, off, 64);
    if (lane == 0) c[pair] = acc + bias[a];
}

// ---------------- K2: MFMA f16 score GEMM, double-buffered ------------------
// block: 256 rows x 256 cols, 512 threads (8 waves, 4x2), BK=32
// One B buffer = 4*256*8 = 8192 halfs (16 KB). Buffer offset = buf*8192.
__global__ __launch_bounds__(512, 2) void k2_mfma(const float* __restrict__ h_i,
                                                  const _Float16* __restrict__ W16,
                                                  const float* __restrict__ c,
                                                  const float* __restrict__ u,
                                                  float* __restrict__ y) {
    __shared__ _Float16 Alds[2][4][256][8];   // 32 KB
    __shared__ _Float16 Blds[2][4][256][8];   // 32 KB
    __shared__ float c_s[AA], u_s[AA];
    __shared__ float red[2][256];

    const int tid = threadIdx.x;
    const int lane = tid & 63;
    const int wave = tid >> 6;
    const int wr = wave >> 1;              // 0..3 -> 64-row slab
    const int wc = wave & 1;               // 0..1 -> 128-col slab
    const int r0 = blockIdx.x * 256;
    const int batch = r0 / SS;

    if (tid < AA) { c_s[tid] = c[batch * AA + tid]; u_s[tid] = u[tid]; }

    f32x4 acc[4][8];
#pragma unroll
    for (int rf = 0; rf < 4; ++rf)
#pragma unroll
        for (int cf = 0; cf < 8; ++cf) acc[rf][cf] = (f32x4){0.f, 0.f, 0.f, 0.f};

    const int arow = tid >> 2;             // 0..127
    const int akslot = tid & 3;            // 0..3
    const float* Abase  = h_i + (size_t)(r0 + arow) * HH + akslot * 8;
    const float* Abase2 = Abase + (size_t)128 * HH;

    const int bslot0 = __builtin_amdgcn_readfirstlane(wave * 64);
    const int bslot1 = __builtin_amdgcn_readfirstlane(512 + wave * 64);
    _Float16* Bflat = &Blds[0][0][0][0];

    const int kq = lane >> 4;
    const int lr = lane & 15;

    // ---- prologue: stage tile 0 into buffer 0
    {
        int sl = bslot0 + lane;
        int col = sl & 255, ks = sl >> 8;
        async_lds16(W16 + (size_t)col * HH + ks * 8, Bflat + (size_t)bslot0 * 8);
        sl = bslot1 + lane; col = sl & 255; ks = sl >> 8;
        async_lds16(W16 + (size_t)col * HH + ks * 8, Bflat + (size_t)bslot1 * 8);

        float4 v0 = *reinterpret_cast<const float4*>(Abase);
        float4 v1 = *reinterpret_cast<const float4*>(Abase + 4);
        float4 v2 = *reinterpret_cast<const float4*>(Abase2);
        float4 v3 = *reinterpret_cast<const float4*>(Abase2 + 4);
        half8 h;
        h[0] = (_Float16)v0.x; h[1] = (_Float16)v0.y;
        h[2] = (_Float16)v0.z; h[3] = (_Float16)v0.w;
        h[4] = (_Float16)v1.x; h[5] = (_Float16)v1.y;
        h[6] = (_Float16)v1.z; h[7] = (_Float16)v1.w;
        *reinterpret_cast<half8*>(&Alds[0][akslot][arow][0]) = h;
        h[0] = (_Float16)v2.x; h[1] = (_Float16)v2.y;
        h[2] = (_Float16)v2.z; h[3] = (_Float16)v2.w;
        h[4] = (_Float16)v3.x; h[5] = (_Float16)v3.y;
        h[6] = (_Float16)v3.z; h[7] = (_Float16)v3.w;
        *reinterpret_cast<half8*>(&Alds[0][akslot][arow + 128][0]) = h;
    }
    __syncthreads();

    for (int t = 0; t < HH / BK; ++t) {
        const int cur = t & 1, nxt = cur ^ 1;
        const int k1 = (t + 1) * BK;
        float4 v0, v1, v2, v3;
        if (t < HH / BK - 1) {
            // issue next B tile (async -> LDS, CORRECT buffer stride 8192) and
            // next A tile (-> regs) EARLY so HBM latency hides under MFMA
            int sl = bslot0 + lane;
            int col = sl & 255, ks = sl >> 8;
            async_lds16(W16 + (size_t)col * HH + k1 + ks * 8,
                        Bflat + (size_t)nxt * 8192 + (size_t)bslot0 * 8);
            sl = bslot1 + lane; col = sl & 255; ks = sl >> 8;
            async_lds16(W16 + (size_t)col * HH + k1 + ks * 8,
                        Bflat + (size_t)nxt * 8192 + (size_t)bslot1 * 8);
            v0 = *reinterpret_cast<const float4*>(Abase + k1);
            v1 = *reinterpret_cast<const float4*>(Abase + k1 + 4);
            v2 = *reinterpret_cast<const float4*>(Abase2 + k1);
            v3 = *reinterpret_cast<const float4*>(Abase2 + k1 + 4);
        }

        half8 af[4], bf[8];
#pragma unroll
        for (int rf = 0; rf < 4; ++rf)
            af[rf] = *reinterpret_cast<half8*>(&Alds[cur][kq][wr * 64 + rf * 16 + lr][0]);
#pragma unroll
        for (int cf = 0; cf < 8; ++cf)
            bf[cf] = *reinterpret_cast<half8*>(&Blds[cur][kq][wc * 128 + cf * 16 + lr][0]);
#pragma unroll
        for (int rf = 0; rf < 4; ++rf)
#pragma unroll
            for (int cf = 0; cf < 8; ++cf)
                acc[rf][cf] = __builtin_amdgcn_mfma_f32_16x16x32_f16(
                    af[rf], bf[cf], acc[rf][cf], 0, 0, 0);

        if (t < HH / BK - 1) {
            half8 h;
            h[0] = (_Float16)v0.x; h[1] = (_Float16)v0.y;
            h[2] = (_Float16)v0.z; h[3] = (_Float16)v0.w;
            h[4] = (_Float16)v1.x; h[5] = (_Float16)v1.y;
            h[6] = (_Float16)v1.z; h[7] = (_Float16)v1.w;
            *reinterpret_cast<half8*>(&Alds[nxt][akslot][arow][0]) = h;
            h[0] = (_Float16)v2.x; h[1] = (_Float16)v2.y;
            h[2] = (_Float16)v2.z; h[3] = (_Float16)v2.w;
            h[4] = (_Float16)v3.x; h[5] = (_Float16)v3.y;
            h[6] = (_Float16)v3.z; h[7] = (_Float16)v3.w;
            *reinterpret_cast<half8*>(&Alds[nxt][akslot][arow + 128][0]) = h;
        }
        __syncthreads();
    }

    // ---- epilogue: z += c[a]; y-row partial = sum_a tanh(z)*u[a]
#pragma unroll
    for (int rf = 0; rf < 4; ++rf) {
#pragma unroll
        for (int j = 0; j < 4; ++j) {
            float v = 0.f;
#pragma unroll
            for (int cf = 0; cf < 8; ++cf) {
                int col = wc * 128 + cf * 16 + lr;
                float z = acc[rf][cf][j] + c_s[col];
                v += tanhf(z) * u_s[col];
            }
            v += __shfl_xor(v, 1, 64);
            v += __shfl_xor(v, 2, 64);
            v += __shfl_xor(v, 4, 64);
            v += __shfl_xor(v, 8, 64);
            if (lr == 0) red[wc][wr * 64 + rf * 16 + kq * 4 + j] = v;
        }
    }
    __syncthreads();
    if (tid < 256) y[r0 + tid] = red[0][tid] + red[1][tid];
}

// ---------------- K3: cross-batch scatter + mask + row softmax --------------
__global__ __launch_bounds__(256) void k3_softmax(const float* __restrict__ y,
                                                  const int* __restrict__ mask,
                                                  float* __restrict__ alpha) {
    const int b = blockIdx.x;
    const int tid = threadIdx.x;
    float beta[8];
    float mx = -INFINITY;
#pragma unroll
    for (int i = 0; i < 8; ++i) {
        int s = tid + i * 256;
        int cnt = 0;
        for (int bb = 0; bb <= b; ++bb) cnt += (mask[bb * SS + s] != 0);
        int p = cnt - 1; if (p < 0) p = 0;
        float v = (mask[b * SS + s] != 0) ? y[p * SS + s] : NEGV;
        beta[i] = v;
        mx = fmaxf(mx, v);
    }
    __shared__ float sm[4], ssum[4];
    for (int off = 32; off; off >>= 1) mx = fmaxf(mx, __shfl_xor(mx, off, 64));
    if ((tid & 63) == 0) sm[tid >> 6] = mx;
    __syncthreads();
    mx = fmaxf(fmaxf(sm[0], sm[1]), fmaxf(sm[2], sm[3]));

    float e[8];
    float sum = 0.f;
#pragma unroll
    for (int i = 0; i < 8; ++i) { e[i] = expf(beta[i] - mx); sum += e[i]; }
    for (int off = 32; off; off >>= 1) sum += __shfl_xor(sum, off, 64);
    if ((tid & 63) == 0) ssum[tid >> 6] = sum;
    __syncthreads();
    sum = ssum[0] + ssum[1] + ssum[2] + ssum[3];
    float inv = 1.f / sum;
#pragma unroll
    for (int i = 0; i < 8; ++i) alpha[b * SS + tid + i * 256] = e[i] * inv;
}

// ---------------- K4a: skip alpha==0 rows via ballot compaction -------------
#define CH 32
#define SCH (SS / CH)  // 64
__global__ __launch_bounds__(256) void k4a_partial(const float* __restrict__ h_i,
                                                   const float* __restrict__ alpha,
                                                   float* __restrict__ partial) {
    const int b = blockIdx.x >> 5;
    const int ch = blockIdx.x & (CH - 1);
    const int tid = threadIdx.x;
    __shared__ float aval[SCH];
    __shared__ int slist[SCH];
    __shared__ int mcnt;

    float a = 0.f;
    bool nz = false;
    if (tid < SCH) {
        a = alpha[b * SS + ch * SCH + tid];
        nz = (a != 0.f);     // masked-out -> expf underflows to exactly 0
    }
    unsigned long long msk = __ballot(nz);   // wave 0 == tid 0..63
    if (tid < SCH) {
        int off = __popcll(msk & ((1ull << tid) - 1));
        if (nz) { slist[off] = tid; aval[off] = a; }
        if (tid == 0) mcnt = __popcll(msk);
    }
    __syncthreads();
    const int m = mcnt;
    const float* base = h_i + (size_t)b * SS * HH + (size_t)ch * SCH * HH;
    f32x4 acc = {0.f, 0.f, 0.f, 0.f};
    for (int i = 0; i < m; ++i) {
        float av = aval[i];
        const float4 v = *reinterpret_cast<const float4*>(
            &base[(size_t)slist[i] * HH + tid * 4]);
        acc[0] += av * v.x; acc[1] += av * v.y;
        acc[2] += av * v.z; acc[3] += av * v.w;
    }
    *reinterpret_cast<f32x4*>(&partial[((size_t)(b * CH + ch)) * HH + tid * 4]) = acc;
}

// ---------------- K4b: out[b,h] = sum_ch partial[b,ch,h] --------------------
__global__ __launch_bounds__(256) void k4b_reduce(const float* __restrict__ partial,
                                                  float* __restrict__ out) {
    int i = blockIdx.x * 256 + threadIdx.x;   // 0..32767
    int b = i >> 10, h = i & (HH - 1);
    float s = 0.f;
#pragma unroll
    for (int ch = 0; ch < CH; ++ch)
        s += partial[((size_t)(b * CH + ch)) * HH + h];
    out[i] = s;
}

extern "C" void kernel_launch(void* const* d_in, const int* in_sizes, int n_in,
                              void* d_out, int out_size, void* d_ws, size_t ws_size,
                              hipStream_t stream) {
    const float* h_i  = (const float*)d_in[0];
    const float* h_t  = (const float*)d_in[1];
    const int*   mask = (const int*)d_in[2];
    const float* W    = (const float*)d_in[3];
    const float* bias = (const float*)d_in[4];
    const float* u    = (const float*)d_in[5];
    float* out = (float*)d_out;

    float* c       = (float*)d_ws;                 // 8192
    float* y       = c + BB * AA;                  // 65536
    float* alpha   = y + BB * SS;                  // 65536
    float* partial = alpha + BB * SS;              // B*CH*H = 1048576
    _Float16* W16  = (_Float16*)(partial + BB * CH * HH);  // 262144 f16

    k0_w16<<<(AA * HH) / 256, 256, 0, stream>>>(W, W16);
    k1_ctx<<<(BB * AA) / 4, 256, 0, stream>>>(h_t, W, bias, c);
    k2_mfma<<<(BB * SS) / 256, 512, 0, stream>>>(h_i, W16, c, u, y);
    k3_softmax<<<BB, 256, 0, stream>>>(y, mask, alpha);
    k4a_partial<<<BB * CH, 256, 0, stream>>>(h_i, alpha, partial);
    k4b_reduce<<<(BB * HH) / 256, 256, 0, stream>>>(partial, out);
}

// Round 6
// 154.649 us; speedup vs baseline: 4.2066x; 1.0351x over previous
//
#include <hip/hip_runtime.h>
#include <math.h>

#define BB 32
#define SS 2048
#define HH 1024
#define AA 256
#define NEGV (-1e20f)
#define BK 32

typedef _Float16 half8 __attribute__((ext_vector_type(8)));
typedef float f32x4 __attribute__((ext_vector_type(4)));

__device__ inline void async_lds16(const void* g, void* l) {
    __builtin_amdgcn_global_load_lds(
        (const __attribute__((address_space(1))) unsigned int*)g,
        (__attribute__((address_space(3))) unsigned int*)l, 16, 0, 0);
}

// ---------------- K0: cast W1 (first H cols of W) to f16 --------------------
__global__ __launch_bounds__(256) void k0_w16(const float* __restrict__ W,
                                              _Float16* __restrict__ W16) {
    int idx = blockIdx.x * 256 + threadIdx.x;     // < A*H = 262144
    int a = idx >> 10;
    int k = idx & (HH - 1);
    W16[idx] = (_Float16)W[(size_t)a * 2 * HH + k];
}

// ---------------- K1: c[b,a] = bias[a] + dot(h_t[b,:], W[a, H:2H]) ----------
__global__ __launch_bounds__(256) void k1_ctx(const float* __restrict__ h_t,
                                              const float* __restrict__ W,
                                              const float* __restrict__ bias,
                                              float* __restrict__ c) {
    int wave = threadIdx.x >> 6;
    int lane = threadIdx.x & 63;
    int pair = blockIdx.x * 4 + wave;
    if (pair >= BB * AA) return;
    int b = pair >> 8;
    int a = pair & (AA - 1);
    const float* ht = h_t + (size_t)b * HH;
    const float* w2 = W + (size_t)a * 2 * HH + HH;
    float acc = 0.f;
    for (int k = lane; k < HH; k += 64)
        acc += ht[k] * w2[k];
    for (int off = 32; off; off >>= 1)
        acc += __shfl_down(acc, off, 64);
    if (lane == 0) c[pair] = acc + bias[a];
}

// ---------------- KC: per-b compaction of needed columns {s: count[s] > b} --
// y[p,s] is only read by k3 for p < count[s] (scatter ranks masked batches).
__global__ __launch_bounds__(256) void kc_compact(const int* __restrict__ mask,
                                                  int* __restrict__ sList,
                                                  int* __restrict__ cntb) {
    const int b = blockIdx.x;
    const int tid = threadIdx.x;
    __shared__ int lcnt;
    if (tid == 0) lcnt = 0;
    __syncthreads();
    int* lst = sList + b * SS;
#pragma unroll
    for (int i = 0; i < 8; ++i) {
        int s = tid + i * 256;
        int cnt = 0;
        for (int bb = 0; bb < BB; ++bb) cnt += (mask[bb * SS + s] != 0);
        if (cnt > b) { int p = atomicAdd(&lcnt, 1); lst[p] = s; }
    }
    __syncthreads();
    const int m = lcnt;
    if (tid == 0) cntb[b] = m;
    if (m > 0) {
        int padded = (m + 255) & ~255;
        int first = lst[0];
        for (int j = m + tid; j < padded; j += 256) lst[j] = first;
    }
}

// ---------------- KD: tile-base prefix over batches -------------------------
__global__ void kd_prefix(const int* __restrict__ cntb, int* __restrict__ tileBase) {
    if (threadIdx.x == 0 && blockIdx.x == 0) {
        int acc = 0;
        for (int b = 0; b < BB; ++b) { tileBase[b] = acc; acc += (cntb[b] + 255) >> 8; }
        tileBase[BB] = acc;
    }
}

// ---------------- K2: MFMA f16 score GEMM over needed rows only -------------
// block: 256 gathered rows (one batch) x 256 cols, 512 threads, BK=32, dbuf
__global__ __launch_bounds__(512, 2) void k2_mfma(const float* __restrict__ h_i,
                                                  const _Float16* __restrict__ W16,
                                                  const float* __restrict__ c,
                                                  const float* __restrict__ u,
                                                  const int* __restrict__ sList,
                                                  const int* __restrict__ tileBase,
                                                  float* __restrict__ y) {
    __shared__ _Float16 Alds[2][4][256][8];   // 32 KB
    __shared__ _Float16 Blds[2][4][256][8];   // 32 KB
    __shared__ float c_s[AA], u_s[AA];
    __shared__ float red[2][256];
    __shared__ int s_idx[256];

    const int t = blockIdx.x;
    if (t >= tileBase[BB]) return;
    int b = 0;
    while (t >= tileBase[b + 1]) ++b;
    const int ti = t - tileBase[b];

    const int tid = threadIdx.x;
    const int lane = tid & 63;
    const int wave = tid >> 6;
    const int wr = wave >> 1;              // 0..3 -> 64-row slab
    const int wc = wave & 1;               // 0..1 -> 128-col slab

    if (tid < 256) s_idx[tid] = sList[b * SS + ti * 256 + tid];
    if (tid < AA) { c_s[tid] = c[b * AA + tid]; u_s[tid] = u[tid]; }
    __syncthreads();   // s_idx ready before address calc

    f32x4 acc[4][8];
#pragma unroll
    for (int rf = 0; rf < 4; ++rf)
#pragma unroll
        for (int cf = 0; cf < 8; ++cf) acc[rf][cf] = (f32x4){0.f, 0.f, 0.f, 0.f};

    const int arow = tid >> 2;             // 0..127
    const int akslot = tid & 3;            // 0..3
    const float* Abase  = h_i + ((size_t)b * SS + s_idx[arow]) * HH + akslot * 8;
    const float* Abase2 = h_i + ((size_t)b * SS + s_idx[arow + 128]) * HH + akslot * 8;

    const int bslot0 = __builtin_amdgcn_readfirstlane(wave * 64);
    const int bslot1 = __builtin_amdgcn_readfirstlane(512 + wave * 64);
    _Float16* Bflat = &Blds[0][0][0][0];

    const int kq = lane >> 4;
    const int lr = lane & 15;

    // ---- prologue: stage tile 0 into buffer 0
    {
        int sl = bslot0 + lane;
        int col = sl & 255, ks = sl >> 8;
        async_lds16(W16 + (size_t)col * HH + ks * 8, Bflat + (size_t)bslot0 * 8);
        sl = bslot1 + lane; col = sl & 255; ks = sl >> 8;
        async_lds16(W16 + (size_t)col * HH + ks * 8, Bflat + (size_t)bslot1 * 8);

        float4 v0 = *reinterpret_cast<const float4*>(Abase);
        float4 v1 = *reinterpret_cast<const float4*>(Abase + 4);
        float4 v2 = *reinterpret_cast<const float4*>(Abase2);
        float4 v3 = *reinterpret_cast<const float4*>(Abase2 + 4);
        half8 h;
        h[0] = (_Float16)v0.x; h[1] = (_Float16)v0.y;
        h[2] = (_Float16)v0.z; h[3] = (_Float16)v0.w;
        h[4] = (_Float16)v1.x; h[5] = (_Float16)v1.y;
        h[6] = (_Float16)v1.z; h[7] = (_Float16)v1.w;
        *reinterpret_cast<half8*>(&Alds[0][akslot][arow][0]) = h;
        h[0] = (_Float16)v2.x; h[1] = (_Float16)v2.y;
        h[2] = (_Float16)v2.z; h[3] = (_Float16)v2.w;
        h[4] = (_Float16)v3.x; h[5] = (_Float16)v3.y;
        h[6] = (_Float16)v3.z; h[7] = (_Float16)v3.w;
        *reinterpret_cast<half8*>(&Alds[0][akslot][arow + 128][0]) = h;
    }
    __syncthreads();

    for (int t2 = 0; t2 < HH / BK; ++t2) {
        const int cur = t2 & 1, nxt = cur ^ 1;
        const int k1 = (t2 + 1) * BK;
        float4 v0, v1, v2, v3;
        if (t2 < HH / BK - 1) {
            int sl = bslot0 + lane;
            int col = sl & 255, ks = sl >> 8;
            async_lds16(W16 + (size_t)col * HH + k1 + ks * 8,
                        Bflat + (size_t)nxt * 8192 + (size_t)bslot0 * 8);
            sl = bslot1 + lane; col = sl & 255; ks = sl >> 8;
            async_lds16(W16 + (size_t)col * HH + k1 + ks * 8,
                        Bflat + (size_t)nxt * 8192 + (size_t)bslot1 * 8);
            v0 = *reinterpret_cast<const float4*>(Abase + k1);
            v1 = *reinterpret_cast<const float4*>(Abase + k1 + 4);
            v2 = *reinterpret_cast<const float4*>(Abase2 + k1);
            v3 = *reinterpret_cast<const float4*>(Abase2 + k1 + 4);
        }

        half8 af[4], bf[8];
#pragma unroll
        for (int rf = 0; rf < 4; ++rf)
            af[rf] = *reinterpret_cast<half8*>(&Alds[cur][kq][wr * 64 + rf * 16 + lr][0]);
#pragma unroll
        for (int cf = 0; cf < 8; ++cf)
            bf[cf] = *reinterpret_cast<half8*>(&Blds[cur][kq][wc * 128 + cf * 16 + lr][0]);
#pragma unroll
        for (int rf = 0; rf < 4; ++rf)
#pragma unroll
            for (int cf = 0; cf < 8; ++cf)
                acc[rf][cf] = __builtin_amdgcn_mfma_f32_16x16x32_f16(
                    af[rf], bf[cf], acc[rf][cf], 0, 0, 0);

        if (t2 < HH / BK - 1) {
            half8 h;
            h[0] = (_Float16)v0.x; h[1] = (_Float16)v0.y;
            h[2] = (_Float16)v0.z; h[3] = (_Float16)v0.w;
            h[4] = (_Float16)v1.x; h[5] = (_Float16)v1.y;
            h[6] = (_Float16)v1.z; h[7] = (_Float16)v1.w;
            *reinterpret_cast<half8*>(&Alds[nxt][akslot][arow][0]) = h;
            h[0] = (_Float16)v2.x; h[1] = (_Float16)v2.y;
            h[2] = (_Float16)v2.z; h[3] = (_Float16)v2.w;
            h[4] = (_Float16)v3.x; h[5] = (_Float16)v3.y;
            h[6] = (_Float16)v3.z; h[7] = (_Float16)v3.w;
            *reinterpret_cast<half8*>(&Alds[nxt][akslot][arow + 128][0]) = h;
        }
        __syncthreads();
    }

    // ---- epilogue: z += c[a]; y-row = sum_a tanh(z)*u[a]
#pragma unroll
    for (int rf = 0; rf < 4; ++rf) {
#pragma unroll
        for (int j = 0; j < 4; ++j) {
            float v = 0.f;
#pragma unroll
            for (int cf = 0; cf < 8; ++cf) {
                int col = wc * 128 + cf * 16 + lr;
                float z = acc[rf][cf][j] + c_s[col];
                v += tanhf(z) * u_s[col];
            }
            v += __shfl_xor(v, 1, 64);
            v += __shfl_xor(v, 2, 64);
            v += __shfl_xor(v, 4, 64);
            v += __shfl_xor(v, 8, 64);
            if (lr == 0) red[wc][wr * 64 + rf * 16 + kq * 4 + j] = v;
        }
    }
    __syncthreads();
    if (tid < 256) y[(size_t)b * SS + s_idx[tid]] = red[0][tid] + red[1][tid];
}

// ---------------- K3: cross-batch scatter + mask + row softmax --------------
__global__ __launch_bounds__(256) void k3_softmax(const float* __restrict__ y,
                                                  const int* __restrict__ mask,
                                                  float* __restrict__ alpha) {
    const int b = blockIdx.x;
    const int tid = threadIdx.x;
    float beta[8];
    float mx = -INFINITY;
#pragma unroll
    for (int i = 0; i < 8; ++i) {
        int s = tid + i * 256;
        int cnt = 0;
        for (int bb = 0; bb <= b; ++bb) cnt += (mask[bb * SS + s] != 0);
        int p = cnt - 1; if (p < 0) p = 0;
        float v = (mask[b * SS + s] != 0) ? y[p * SS + s] : NEGV;
        beta[i] = v;
        mx = fmaxf(mx, v);
    }
    __shared__ float sm[4], ssum[4];
    for (int off = 32; off; off >>= 1) mx = fmaxf(mx, __shfl_xor(mx, off, 64));
    if ((tid & 63) == 0) sm[tid >> 6] = mx;
    __syncthreads();
    mx = fmaxf(fmaxf(sm[0], sm[1]), fmaxf(sm[2], sm[3]));

    float e[8];
    float sum = 0.f;
#pragma unroll
    for (int i = 0; i < 8; ++i) { e[i] = expf(beta[i] - mx); sum += e[i]; }
    for (int off = 32; off; off >>= 1) sum += __shfl_xor(sum, off, 64);
    if ((tid & 63) == 0) ssum[tid >> 6] = sum;
    __syncthreads();
    sum = ssum[0] + ssum[1] + ssum[2] + ssum[3];
    float inv = 1.f / sum;
#pragma unroll
    for (int i = 0; i < 8; ++i) alpha[b * SS + tid + i * 256] = e[i] * inv;
}

// ---------------- K4a: skip alpha==0 rows via ballot compaction -------------
#define CH 32
#define SCH (SS / CH)  // 64
__global__ __launch_bounds__(256) void k4a_partial(const float* __restrict__ h_i,
                                                   const float* __restrict__ alpha,
                                                   float* __restrict__ partial) {
    const int b = blockIdx.x >> 5;
    const int ch = blockIdx.x & (CH - 1);
    const int tid = threadIdx.x;
    __shared__ float aval[SCH];
    __shared__ int slist[SCH];
    __shared__ int mcnt;

    float a = 0.f;
    bool nz = false;
    if (tid < SCH) {
        a = alpha[b * SS + ch * SCH + tid];
        nz = (a != 0.f);     // masked-out -> expf underflows to exactly 0
    }
    unsigned long long msk = __ballot(nz);   // wave 0 == tid 0..63
    if (tid < SCH) {
        int off = __popcll(msk & ((1ull << tid) - 1));
        if (nz) { slist[off] = tid; aval[off] = a; }
        if (tid == 0) mcnt = __popcll(msk);
    }
    __syncthreads();
    const int m = mcnt;
    const float* base = h_i + (size_t)b * SS * HH + (size_t)ch * SCH * HH;
    f32x4 acc = {0.f, 0.f, 0.f, 0.f};
    for (int i = 0; i < m; ++i) {
        float av = aval[i];
        const float4 v = *reinterpret_cast<const float4*>(
            &base[(size_t)slist[i] * HH + tid * 4]);
        acc[0] += av * v.x; acc[1] += av * v.y;
        acc[2] += av * v.z; acc[3] += av * v.w;
    }
    *reinterpret_cast<f32x4*>(&partial[((size_t)(b * CH + ch)) * HH + tid * 4]) = acc;
}

// ---------------- K4b: out[b,h] = sum_ch partial[b,ch,h] --------------------
__global__ __launch_bounds__(256) void k4b_reduce(const float* __restrict__ partial,
                                                  float* __restrict__ out) {
    int i = blockIdx.x * 256 + threadIdx.x;   // 0..32767
    int b = i >> 10, h = i & (HH - 1);
    float s = 0.f;
#pragma unroll
    for (int ch = 0; ch < CH; ++ch)
        s += partial[((size_t)(b * CH + ch)) * HH + h];
    out[i] = s;
}

extern "C" void kernel_launch(void* const* d_in, const int* in_sizes, int n_in,
                              void* d_out, int out_size, void* d_ws, size_t ws_size,
                              hipStream_t stream) {
    const float* h_i  = (const float*)d_in[0];
    const float* h_t  = (const float*)d_in[1];
    const int*   mask = (const int*)d_in[2];
    const float* W    = (const float*)d_in[3];
    const float* bias = (const float*)d_in[4];
    const float* u    = (const float*)d_in[5];
    float* out = (float*)d_out;

    float* c        = (float*)d_ws;                 // 8192
    float* y        = c + BB * AA;                  // 65536
    float* alpha    = y + BB * SS;                  // 65536
    float* partial  = alpha + BB * SS;              // B*CH*H = 1048576
    _Float16* W16   = (_Float16*)(partial + BB * CH * HH);  // 262144 f16
    int* sList      = (int*)(W16 + AA * HH);        // B*S = 65536 ints
    int* cntb       = sList + BB * SS;              // 32
    int* tileBase   = cntb + BB;                    // 33

    k0_w16<<<(AA * HH) / 256, 256, 0, stream>>>(W, W16);
    kc_compact<<<BB, 256, 0, stream>>>(mask, sList, cntb);
    kd_prefix<<<1, 64, 0, stream>>>(cntb, tileBase);
    k1_ctx<<<(BB * AA) / 4, 256, 0, stream>>>(h_t, W, bias, c);
    k2_mfma<<<256, 512, 0, stream>>>(h_i, W16, c, u, sList, tileBase, y);
    k3_softmax<<<BB, 256, 0, stream>>>(y, mask, alpha);
    k4a_partial<<<BB * CH, 256, 0, stream>>>(h_i, alpha, partial);
    k4b_reduce<<<(BB * HH) / 256, 256, 0, stream>>>(partial, out);
}

// Round 7
// 154.531 us; speedup vs baseline: 4.2098x; 1.0008x over previous
//
#include <hip/hip_runtime.h>
#include <math.h>

#define BB 32
#define SS 2048
#define HH 1024
#define AA 256
#define NEGV (-1e20f)
#define BK 32

typedef _Float16 half8 __attribute__((ext_vector_type(8)));
typedef float f32x4 __attribute__((ext_vector_type(4)));

__device__ inline void async_lds16(const void* g, void* l) {
    __builtin_amdgcn_global_load_lds(
        (const __attribute__((address_space(1))) unsigned int*)g,
        (__attribute__((address_space(3))) unsigned int*)l, 16, 0, 0);
}

// ============ PREP: role A = W16 cast, role B = ctx c[b,a], role C = compact
// blocks [0,1024): W16     blocks [1024,3072): ctx     blocks [3072,3104): compact
__global__ __launch_bounds__(256) void k_prep(const float* __restrict__ W,
                                              const float* __restrict__ h_t,
                                              const float* __restrict__ bias,
                                              const int* __restrict__ mask,
                                              _Float16* __restrict__ W16,
                                              float* __restrict__ c,
                                              int* __restrict__ sList,
                                              int* __restrict__ cntb,
                                              int* __restrict__ pcnt) {
    const int blk = blockIdx.x;
    const int tid = threadIdx.x;
    __shared__ int lcnt;

    if (blk < 1024) {                       // ---- role A: cast W1 to f16
        int idx = blk * 256 + tid;          // < A*H
        int a = idx >> 10;
        int k = idx & (HH - 1);
        W16[idx] = (_Float16)W[(size_t)a * 2 * HH + k];
        return;
    }
    if (blk < 3072) {                       // ---- role B: c[b,a]
        int wave = tid >> 6;
        int lane = tid & 63;
        int pair = (blk - 1024) * 4 + wave; // < B*A = 8192
        int b = pair >> 8;
        int a = pair & (AA - 1);
        const float* ht = h_t + (size_t)b * HH;
        const float* w2 = W + (size_t)a * 2 * HH + HH;
        float acc = 0.f;
        for (int k = lane; k < HH; k += 64)
            acc += ht[k] * w2[k];
        for (int off = 32; off; off >>= 1)
            acc += __shfl_down(acc, off, 64);
        if (lane == 0) c[pair] = acc + bias[a];
        return;
    }
    // ---- role C: per-b prefix counts + compacted column list (pad to 128)
    const int b = blk - 3072;
    if (tid == 0) lcnt = 0;
    __syncthreads();
    int* lst = sList + b * SS;
#pragma unroll
    for (int i = 0; i < 8; ++i) {
        int s = tid + i * 256;
        int pref = 0, tot = 0;
#pragma unroll
        for (int bb = 0; bb < BB; ++bb) {
            int mv = (mask[bb * SS + s] != 0);
            tot += mv;
            if (bb <= b) pref += mv;
        }
        pcnt[b * SS + s] = pref;
        if (tot > b) { int p = atomicAdd(&lcnt, 1); lst[p] = s; }
    }
    __syncthreads();
    const int m = lcnt;
    if (tid == 0) cntb[b] = m;
    if (m > 0) {
        int padded = (m + 127) & ~127;
        int first = lst[0];
        for (int j = m + tid; j < padded; j += 256) lst[j] = first;
    }
}

// ============ K2: MFMA f16 score GEMM over needed rows, 128x256 tile ========
// 256 threads (4 waves 2x2), BK=32, double-buffered. ~272 active blocks.
__global__ __launch_bounds__(256, 2) void k2_mfma(const float* __restrict__ h_i,
                                                  const _Float16* __restrict__ W16,
                                                  const float* __restrict__ c,
                                                  const float* __restrict__ u,
                                                  const int* __restrict__ sList,
                                                  const int* __restrict__ cntb,
                                                  float* __restrict__ y) {
    __shared__ _Float16 Alds[2][4][128][8];   // 16 KB
    __shared__ _Float16 Blds[2][4][256][8];   // 32 KB
    __shared__ float c_s[AA], u_s[AA];
    __shared__ float red[2][128];
    __shared__ int s_idx[128];

    const int t = blockIdx.x;
    int b = -1, ti = 0, acc2 = 0;
    for (int bb = 0; bb < BB; ++bb) {
        int nt = (cntb[bb] + 127) >> 7;
        if (b < 0 && t < acc2 + nt) { b = bb; ti = t - acc2; }
        acc2 += nt;
    }
    if (b < 0) return;

    const int tid = threadIdx.x;
    const int lane = tid & 63;
    const int wave = tid >> 6;
    const int wr = wave >> 1;              // 0..1 -> 64-row slab
    const int wc = wave & 1;               // 0..1 -> 128-col slab

    if (tid < 128) s_idx[tid] = sList[b * SS + ti * 128 + tid];
    c_s[tid] = c[b * AA + tid];
    u_s[tid] = u[tid];
    __syncthreads();

    f32x4 acc[4][8];
#pragma unroll
    for (int rf = 0; rf < 4; ++rf)
#pragma unroll
        for (int cf = 0; cf < 8; ++cf) acc[rf][cf] = (f32x4){0.f, 0.f, 0.f, 0.f};

    const int arow = tid >> 1;             // 0..127
    const int ahalf = tid & 1;             // k-offset 0 / 16 floats
    const float* Abase = h_i + ((size_t)b * SS + s_idx[arow]) * HH + ahalf * 16;

    const int w64 = __builtin_amdgcn_readfirstlane(wave * 64);
    _Float16* Bflat = &Blds[0][0][0][0];   // one buffer = 4*256*8 = 8192 halfs

    const int kq = lane >> 4;
    const int lr = lane & 15;

    // ---- prologue: stage K-tile 0 into buffer 0
    {
#pragma unroll
        for (int i = 0; i < 4; ++i) {
            int sbase = i * 256 + w64;
            int sl = sbase + lane;
            int col = sl & 255, ks = sl >> 8;
            async_lds16(W16 + (size_t)col * HH + ks * 8,
                        Bflat + (size_t)sbase * 8);
        }
        float4 v0 = *reinterpret_cast<const float4*>(Abase);
        float4 v1 = *reinterpret_cast<const float4*>(Abase + 4);
        float4 v2 = *reinterpret_cast<const float4*>(Abase + 8);
        float4 v3 = *reinterpret_cast<const float4*>(Abase + 12);
        half8 h;
        h[0] = (_Float16)v0.x; h[1] = (_Float16)v0.y;
        h[2] = (_Float16)v0.z; h[3] = (_Float16)v0.w;
        h[4] = (_Float16)v1.x; h[5] = (_Float16)v1.y;
        h[6] = (_Float16)v1.z; h[7] = (_Float16)v1.w;
        *reinterpret_cast<half8*>(&Alds[0][2 * ahalf][arow][0]) = h;
        h[0] = (_Float16)v2.x; h[1] = (_Float16)v2.y;
        h[2] = (_Float16)v2.z; h[3] = (_Float16)v2.w;
        h[4] = (_Float16)v3.x; h[5] = (_Float16)v3.y;
        h[6] = (_Float16)v3.z; h[7] = (_Float16)v3.w;
        *reinterpret_cast<half8*>(&Alds[0][2 * ahalf + 1][arow][0]) = h;
    }
    __syncthreads();

    for (int t2 = 0; t2 < HH / BK; ++t2) {
        const int cur = t2 & 1, nxt = cur ^ 1;
        const int k1 = (t2 + 1) * BK;
        float4 v0, v1, v2, v3;
        if (t2 < HH / BK - 1) {
            // issue next B (async->LDS) and next A (->regs) EARLY
#pragma unroll
            for (int i = 0; i < 4; ++i) {
                int sbase = i * 256 + w64;
                int sl = sbase + lane;
                int col = sl & 255, ks = sl >> 8;
                async_lds16(W16 + (size_t)col * HH + k1 + ks * 8,
                            Bflat + (size_t)nxt * 8192 + (size_t)sbase * 8);
            }
            v0 = *reinterpret_cast<const float4*>(Abase + k1);
            v1 = *reinterpret_cast<const float4*>(Abase + k1 + 4);
            v2 = *reinterpret_cast<const float4*>(Abase + k1 + 8);
            v3 = *reinterpret_cast<const float4*>(Abase + k1 + 12);
        }

        half8 af[4], bf[8];
#pragma unroll
        for (int rf = 0; rf < 4; ++rf)
            af[rf] = *reinterpret_cast<half8*>(&Alds[cur][kq][wr * 64 + rf * 16 + lr][0]);
#pragma unroll
        for (int cf = 0; cf < 8; ++cf)
            bf[cf] = *reinterpret_cast<half8*>(&Blds[cur][kq][wc * 128 + cf * 16 + lr][0]);
#pragma unroll
        for (int rf = 0; rf < 4; ++rf)
#pragma unroll
            for (int cf = 0; cf < 8; ++cf)
                acc[rf][cf] = __builtin_amdgcn_mfma_f32_16x16x32_f16(
                    af[rf], bf[cf], acc[rf][cf], 0, 0, 0);

        if (t2 < HH / BK - 1) {
            half8 h;
            h[0] = (_Float16)v0.x; h[1] = (_Float16)v0.y;
            h[2] = (_Float16)v0.z; h[3] = (_Float16)v0.w;
            h[4] = (_Float16)v1.x; h[5] = (_Float16)v1.y;
            h[6] = (_Float16)v1.z; h[7] = (_Float16)v1.w;
            *reinterpret_cast<half8*>(&Alds[nxt][2 * ahalf][arow][0]) = h;
            h[0] = (_Float16)v2.x; h[1] = (_Float16)v2.y;
            h[2] = (_Float16)v2.z; h[3] = (_Float16)v2.w;
            h[4] = (_Float16)v3.x; h[5] = (_Float16)v3.y;
            h[6] = (_Float16)v3.z; h[7] = (_Float16)v3.w;
            *reinterpret_cast<half8*>(&Alds[nxt][2 * ahalf + 1][arow][0]) = h;
        }
        __syncthreads();
    }

    // ---- epilogue: z += c[a]; y-row = sum_a tanh(z)*u[a]
#pragma unroll
    for (int rf = 0; rf < 4; ++rf) {
#pragma unroll
        for (int j = 0; j < 4; ++j) {
            float v = 0.f;
#pragma unroll
            for (int cf = 0; cf < 8; ++cf) {
                int col = wc * 128 + cf * 16 + lr;
                float z = acc[rf][cf][j] + c_s[col];
                v += tanhf(z) * u_s[col];
            }
            v += __shfl_xor(v, 1, 64);
            v += __shfl_xor(v, 2, 64);
            v += __shfl_xor(v, 4, 64);
            v += __shfl_xor(v, 8, 64);
            if (lr == 0) red[wc][wr * 64 + rf * 16 + kq * 4 + j] = v;
        }
    }
    __syncthreads();
    if (tid < 128) y[(size_t)b * SS + s_idx[tid]] = red[0][tid] + red[1][tid];
}

// ============ K3: scatter via pcnt + mask + row softmax =====================
__global__ __launch_bounds__(256) void k3_softmax(const float* __restrict__ y,
                                                  const int* __restrict__ mask,
                                                  const int* __restrict__ pcnt,
                                                  float* __restrict__ alpha) {
    const int b = blockIdx.x;
    const int tid = threadIdx.x;
    float beta[8];
    float mx = -INFINITY;
#pragma unroll
    for (int i = 0; i < 8; ++i) {
        int s = tid + i * 256;
        int p = pcnt[b * SS + s] - 1;
        if (p < 0) p = 0;
        float v = (mask[b * SS + s] != 0) ? y[(size_t)p * SS + s] : NEGV;
        beta[i] = v;
        mx = fmaxf(mx, v);
    }
    __shared__ float sm[4], ssum[4];
    for (int off = 32; off; off >>= 1) mx = fmaxf(mx, __shfl_xor(mx, off, 64));
    if ((tid & 63) == 0) sm[tid >> 6] = mx;
    __syncthreads();
    mx = fmaxf(fmaxf(sm[0], sm[1]), fmaxf(sm[2], sm[3]));

    float e[8];
    float sum = 0.f;
#pragma unroll
    for (int i = 0; i < 8; ++i) { e[i] = expf(beta[i] - mx); sum += e[i]; }
    for (int off = 32; off; off >>= 1) sum += __shfl_xor(sum, off, 64);
    if ((tid & 63) == 0) ssum[tid >> 6] = sum;
    __syncthreads();
    sum = ssum[0] + ssum[1] + ssum[2] + ssum[3];
    float inv = 1.f / sum;
#pragma unroll
    for (int i = 0; i < 8; ++i) alpha[b * SS + tid + i * 256] = e[i] * inv;
}

// ============ K4a: weighted sum, skip alpha==0 rows =========================
#define CH 64
#define SCH (SS / CH)  // 32
__global__ __launch_bounds__(256) void k4a_partial(const float* __restrict__ h_i,
                                                   const float* __restrict__ alpha,
                                                   float* __restrict__ partial) {
    const int b = blockIdx.x >> 6;
    const int ch = blockIdx.x & (CH - 1);
    const int tid = threadIdx.x;
    __shared__ float aval[SCH];
    __shared__ int slist[SCH];
    __shared__ int mcnt;

    float a = 0.f;
    bool nz = false;
    if (tid < SCH) {
        a = alpha[b * SS + ch * SCH + tid];
        nz = (a != 0.f);     // masked-out -> expf underflows to exactly 0
    }
    unsigned long long msk = __ballot(nz);   // wave 0 covers tid 0..63
    if (tid < SCH) {
        int off = __popcll(msk & ((1ull << tid) - 1));
        if (nz) { slist[off] = tid; aval[off] = a; }
        if (tid == 0) mcnt = __popcll(msk);
    }
    __syncthreads();
    const int m = mcnt;
    const float* base = h_i + (size_t)b * SS * HH + (size_t)ch * SCH * HH;
    f32x4 acc = {0.f, 0.f, 0.f, 0.f};
    for (int i = 0; i < m; ++i) {
        float av = aval[i];
        const float4 v = *reinterpret_cast<const float4*>(
            &base[(size_t)slist[i] * HH + tid * 4]);
        acc[0] += av * v.x; acc[1] += av * v.y;
        acc[2] += av * v.z; acc[3] += av * v.w;
    }
    *reinterpret_cast<f32x4*>(&partial[((size_t)(b * CH + ch)) * HH + tid * 4]) = acc;
}

// ============ K4b: out[b,h] = sum_ch partial[b,ch,h] ========================
__global__ __launch_bounds__(256) void k4b_reduce(const float* __restrict__ partial,
                                                  float* __restrict__ out) {
    int i = blockIdx.x * 256 + threadIdx.x;   // 0..32767
    int b = i >> 10, h = i & (HH - 1);
    float s = 0.f;
#pragma unroll
    for (int ch = 0; ch < CH; ++ch)
        s += partial[((size_t)(b * CH + ch)) * HH + h];
    out[i] = s;
}

extern "C" void kernel_launch(void* const* d_in, const int* in_sizes, int n_in,
                              void* d_out, int out_size, void* d_ws, size_t ws_size,
                              hipStream_t stream) {
    const float* h_i  = (const float*)d_in[0];
    const float* h_t  = (const float*)d_in[1];
    const int*   mask = (const int*)d_in[2];
    const float* W    = (const float*)d_in[3];
    const float* bias = (const float*)d_in[4];
    const float* u    = (const float*)d_in[5];
    float* out = (float*)d_out;

    float* c        = (float*)d_ws;                       // 8192
    float* y        = c + BB * AA;                        // 65536
    float* alpha    = y + BB * SS;                        // 65536
    float* partial  = alpha + BB * SS;                    // B*64*H = 2097152
    _Float16* W16   = (_Float16*)(partial + BB * CH * HH);  // 262144 f16
    int* sList      = (int*)(W16 + AA * HH);              // 65536
    int* cntb       = sList + BB * SS;                    // 32
    int* pcnt       = cntb + BB;                          // 65536

    k_prep<<<3104, 256, 0, stream>>>(W, h_t, bias, mask, W16, c, sList, cntb, pcnt);
    k2_mfma<<<512, 256, 0, stream>>>(h_i, W16, c, u, sList, cntb, y);
    k3_softmax<<<BB, 256, 0, stream>>>(y, mask, pcnt, alpha);
    k4a_partial<<<BB * CH, 256, 0, stream>>>(h_i, alpha, partial);
    k4b_reduce<<<(BB * HH) / 256, 256, 0, stream>>>(partial, out);
}

// Round 9
// 153.427 us; speedup vs baseline: 4.2402x; 1.0072x over previous
//
#include <hip/hip_runtime.h>
#include <math.h>

#define BB 32
#define SS 2048
#define HH 1024
#define AA 256
#define NEGV (-1e20f)
#define BK 32

typedef _Float16 half8 __attribute__((ext_vector_type(8)));
typedef float f32x4 __attribute__((ext_vector_type(4)));

__device__ inline void async_lds16(const void* g, void* l) {
    __builtin_amdgcn_global_load_lds(
        (const __attribute__((address_space(1))) unsigned int*)g,
        (__attribute__((address_space(3))) unsigned int*)l, 16, 0, 0);
}

// ============ PREP: role A = W16 cast, role B = ctx c[b,a], role C = compact
// blocks [0,1024): W16     blocks [1024,3072): ctx     blocks [3072,3104): compact
__global__ __launch_bounds__(256) void k_prep(const float* __restrict__ W,
                                              const float* __restrict__ h_t,
                                              const float* __restrict__ bias,
                                              const int* __restrict__ mask,
                                              _Float16* __restrict__ W16,
                                              float* __restrict__ c,
                                              int* __restrict__ sList,
                                              int* __restrict__ cntb,
                                              int* __restrict__ pcnt) {
    const int blk = blockIdx.x;
    const int tid = threadIdx.x;
    __shared__ int lcnt;

    if (blk < 1024) {                       // ---- role A: cast W1 to f16
        int idx = blk * 256 + tid;          // < A*H
        int a = idx >> 10;
        int k = idx & (HH - 1);
        W16[idx] = (_Float16)W[(size_t)a * 2 * HH + k];
        return;
    }
    if (blk < 3072) {                       // ---- role B: c[b,a]
        int wave = tid >> 6;
        int lane = tid & 63;
        int pair = (blk - 1024) * 4 + wave; // < B*A = 8192
        int b = pair >> 8;
        int a = pair & (AA - 1);
        const float* ht = h_t + (size_t)b * HH;
        const float* w2 = W + (size_t)a * 2 * HH + HH;
        float acc = 0.f;
        for (int k = lane; k < HH; k += 64)
            acc += ht[k] * w2[k];
        for (int off = 32; off; off >>= 1)
            acc += __shfl_down(acc, off, 64);
        if (lane == 0) c[pair] = acc + bias[a];
        return;
    }
    // ---- role C: per-b prefix counts + compacted column list (pad to 128)
    const int b = blk - 3072;
    if (tid == 0) lcnt = 0;
    __syncthreads();
    int* lst = sList + b * SS;
#pragma unroll
    for (int i = 0; i < 8; ++i) {
        int s = tid + i * 256;
        int pref = 0, tot = 0;
#pragma unroll
        for (int bb = 0; bb < BB; ++bb) {
            int mv = (mask[bb * SS + s] != 0);
            tot += mv;
            if (bb <= b) pref += mv;
        }
        pcnt[b * SS + s] = pref;
        if (tot > b) { int p = atomicAdd(&lcnt, 1); lst[p] = s; }
    }
    __syncthreads();
    const int m = lcnt;
    if (tid == 0) cntb[b] = m;
    if (m > 0) {
        int padded = (m + 127) & ~127;
        int first = lst[0];
        for (int j = m + tid; j < padded; j += 256) lst[j] = first;
    }
}

// ============ K2: MFMA f16 score GEMM over needed rows, 128x256 tile ========
// 256 threads (4 waves 2x2), BK=32, double-buffered. ~272 active blocks.
__global__ __launch_bounds__(256, 2) void k2_mfma(const float* __restrict__ h_i,
                                                  const _Float16* __restrict__ W16,
                                                  const float* __restrict__ c,
                                                  const float* __restrict__ u,
                                                  const int* __restrict__ sList,
                                                  const int* __restrict__ cntb,
                                                  float* __restrict__ y) {
    __shared__ _Float16 Alds[2][4][128][8];   // 16 KB
    __shared__ _Float16 Blds[2][4][256][8];   // 32 KB
    __shared__ float c_s[AA], u_s[AA];
    __shared__ float red[2][128];
    __shared__ int s_idx[128];

    const int t = blockIdx.x;
    int b = -1, ti = 0, acc2 = 0;
    for (int bb = 0; bb < BB; ++bb) {
        int nt = (cntb[bb] + 127) >> 7;
        if (b < 0 && t < acc2 + nt) { b = bb; ti = t - acc2; }
        acc2 += nt;
    }
    if (b < 0) return;

    const int tid = threadIdx.x;
    const int lane = tid & 63;
    const int wave = tid >> 6;
    const int wr = wave >> 1;              // 0..1 -> 64-row slab
    const int wc = wave & 1;               // 0..1 -> 128-col slab

    if (tid < 128) s_idx[tid] = sList[b * SS + ti * 128 + tid];
    c_s[tid] = c[b * AA + tid];
    u_s[tid] = u[tid];
    __syncthreads();

    f32x4 acc[4][8];
#pragma unroll
    for (int rf = 0; rf < 4; ++rf)
#pragma unroll
        for (int cf = 0; cf < 8; ++cf) acc[rf][cf] = (f32x4){0.f, 0.f, 0.f, 0.f};

    const int arow = tid >> 1;             // 0..127
    const int ahalf = tid & 1;             // k-offset 0 / 16 floats
    const float* Abase = h_i + ((size_t)b * SS + s_idx[arow]) * HH + ahalf * 16;

    const int w64 = __builtin_amdgcn_readfirstlane(wave * 64);
    _Float16* Bflat = &Blds[0][0][0][0];   // one buffer = 4*256*8 = 8192 halfs

    const int kq = lane >> 4;
    const int lr = lane & 15;

    // ---- prologue: stage K-tile 0 into buffer 0
    {
#pragma unroll
        for (int i = 0; i < 4; ++i) {
            int sbase = i * 256 + w64;
            int sl = sbase + lane;
            int col = sl & 255, ks = sl >> 8;
            async_lds16(W16 + (size_t)col * HH + ks * 8,
                        Bflat + (size_t)sbase * 8);
        }
        float4 v0 = *reinterpret_cast<const float4*>(Abase);
        float4 v1 = *reinterpret_cast<const float4*>(Abase + 4);
        float4 v2 = *reinterpret_cast<const float4*>(Abase + 8);
        float4 v3 = *reinterpret_cast<const float4*>(Abase + 12);
        half8 h;
        h[0] = (_Float16)v0.x; h[1] = (_Float16)v0.y;
        h[2] = (_Float16)v0.z; h[3] = (_Float16)v0.w;
        h[4] = (_Float16)v1.x; h[5] = (_Float16)v1.y;
        h[6] = (_Float16)v1.z; h[7] = (_Float16)v1.w;
        *reinterpret_cast<half8*>(&Alds[0][2 * ahalf][arow][0]) = h;
        h[0] = (_Float16)v2.x; h[1] = (_Float16)v2.y;
        h[2] = (_Float16)v2.z; h[3] = (_Float16)v2.w;
        h[4] = (_Float16)v3.x; h[5] = (_Float16)v3.y;
        h[6] = (_Float16)v3.z; h[7] = (_Float16)v3.w;
        *reinterpret_cast<half8*>(&Alds[0][2 * ahalf + 1][arow][0]) = h;
    }
    __syncthreads();

    for (int t2 = 0; t2 < HH / BK; ++t2) {
        const int cur = t2 & 1, nxt = cur ^ 1;
        const int k1 = (t2 + 1) * BK;
        float4 v0, v1, v2, v3;
        if (t2 < HH / BK - 1) {
            // issue next B (async->LDS) and next A (->regs) EARLY
#pragma unroll
            for (int i = 0; i < 4; ++i) {
                int sbase = i * 256 + w64;
                int sl = sbase + lane;
                int col = sl & 255, ks = sl >> 8;
                async_lds16(W16 + (size_t)col * HH + k1 + ks * 8,
                            Bflat + (size_t)nxt * 8192 + (size_t)sbase * 8);
            }
            v0 = *reinterpret_cast<const float4*>(Abase + k1);
            v1 = *reinterpret_cast<const float4*>(Abase + k1 + 4);
            v2 = *reinterpret_cast<const float4*>(Abase + k1 + 8);
            v3 = *reinterpret_cast<const float4*>(Abase + k1 + 12);
        }

        half8 af[4], bf[8];
#pragma unroll
        for (int rf = 0; rf < 4; ++rf)
            af[rf] = *reinterpret_cast<half8*>(&Alds[cur][kq][wr * 64 + rf * 16 + lr][0]);
#pragma unroll
        for (int cf = 0; cf < 8; ++cf)
            bf[cf] = *reinterpret_cast<half8*>(&Blds[cur][kq][wc * 128 + cf * 16 + lr][0]);
#pragma unroll
        for (int rf = 0; rf < 4; ++rf)
#pragma unroll
            for (int cf = 0; cf < 8; ++cf)
                acc[rf][cf] = __builtin_amdgcn_mfma_f32_16x16x32_f16(
                    af[rf], bf[cf], acc[rf][cf], 0, 0, 0);

        if (t2 < HH / BK - 1) {
            half8 h;
            h[0] = (_Float16)v0.x; h[1] = (_Float16)v0.y;
            h[2] = (_Float16)v0.z; h[3] = (_Float16)v0.w;
            h[4] = (_Float16)v1.x; h[5] = (_Float16)v1.y;
            h[6] = (_Float16)v1.z; h[7] = (_Float16)v1.w;
            *reinterpret_cast<half8*>(&Alds[nxt][2 * ahalf][arow][0]) = h;
            h[0] = (_Float16)v2.x; h[1] = (_Float16)v2.y;
            h[2] = (_Float16)v2.z; h[3] = (_Float16)v2.w;
            h[4] = (_Float16)v3.x; h[5] = (_Float16)v3.y;
            h[6] = (_Float16)v3.z; h[7] = (_Float16)v3.w;
            *reinterpret_cast<half8*>(&Alds[nxt][2 * ahalf + 1][arow][0]) = h;
        }
        __syncthreads();
    }

    // ---- epilogue: z += c[a]; y-row = sum_a tanh(z)*u[a]
#pragma unroll
    for (int rf = 0; rf < 4; ++rf) {
#pragma unroll
        for (int j = 0; j < 4; ++j) {
            float v = 0.f;
#pragma unroll
            for (int cf = 0; cf < 8; ++cf) {
                int col = wc * 128 + cf * 16 + lr;
                float z = acc[rf][cf][j] + c_s[col];
                v += tanhf(z) * u_s[col];
            }
            v += __shfl_xor(v, 1, 64);
            v += __shfl_xor(v, 2, 64);
            v += __shfl_xor(v, 4, 64);
            v += __shfl_xor(v, 8, 64);
            if (lr == 0) red[wc][wr * 64 + rf * 16 + kq * 4 + j] = v;
        }
    }
    __syncthreads();
    if (tid < 128) y[(size_t)b * SS + s_idx[tid]] = red[0][tid] + red[1][tid];
}

// ============ K3: scatter via pcnt + mask + row softmax =====================
__global__ __launch_bounds__(256) void k3_softmax(const float* __restrict__ y,
                                                  const int* __restrict__ mask,
                                                  const int* __restrict__ pcnt,
                                                  float* __restrict__ alpha) {
    const int b = blockIdx.x;
    const int tid = threadIdx.x;
    float beta[8];
    float mx = -INFINITY;
#pragma unroll
    for (int i = 0; i < 8; ++i) {
        int s = tid + i * 256;
        int p = pcnt[b * SS + s] - 1;
        if (p < 0) p = 0;
        float v = (mask[b * SS + s] != 0) ? y[(size_t)p * SS + s] : NEGV;
        beta[i] = v;
        mx = fmaxf(mx, v);
    }
    __shared__ float sm[4], ssum[4];
    for (int off = 32; off; off >>= 1) mx = fmaxf(mx, __shfl_xor(mx, off, 64));
    if ((tid & 63) == 0) sm[tid >> 6] = mx;
    __syncthreads();
    mx = fmaxf(fmaxf(sm[0], sm[1]), fmaxf(sm[2], sm[3]));

    float e[8];
    float sum = 0.f;
#pragma unroll
    for (int i = 0; i < 8; ++i) { e[i] = expf(beta[i] - mx); sum += e[i]; }
    for (int off = 32; off; off >>= 1) sum += __shfl_xor(sum, off, 64);
    if ((tid & 63) == 0) ssum[tid >> 6] = sum;
    __syncthreads();
    sum = ssum[0] + ssum[1] + ssum[2] + ssum[3];
    float inv = 1.f / sum;
#pragma unroll
    for (int i = 0; i < 8; ++i) alpha[b * SS + tid + i * 256] = e[i] * inv;
}

// ============ K4a: weighted sum, skip alpha==0 rows =========================
#define CH 64
#define SCH (SS / CH)  // 32
__global__ __launch_bounds__(256) void k4a_partial(const float* __restrict__ h_i,
                                                   const float* __restrict__ alpha,
                                                   float* __restrict__ partial) {
    const int b = blockIdx.x >> 6;
    const int ch = blockIdx.x & (CH - 1);
    const int tid = threadIdx.x;
    __shared__ float aval[SCH];
    __shared__ int slist[SCH];
    __shared__ int mcnt;

    float a = 0.f;
    bool nz = false;
    if (tid < SCH) {
        a = alpha[b * SS + ch * SCH + tid];
        nz = (a != 0.f);     // masked-out -> expf underflows to exactly 0
    }
    unsigned long long msk = __ballot(nz);   // wave 0 covers tid 0..63
    if (tid < SCH) {
        int off = __popcll(msk & ((1ull << tid) - 1));
        if (nz) { slist[off] = tid; aval[off] = a; }
        if (tid == 0) mcnt = __popcll(msk);
    }
    __syncthreads();
    const int m = mcnt;
    const float* base = h_i + (size_t)b * SS * HH + (size_t)ch * SCH * HH;
    f32x4 acc = {0.f, 0.f, 0.f, 0.f};
    for (int i = 0; i < m; ++i) {
        float av = aval[i];
        const float4 v = *reinterpret_cast<const float4*>(
            &base[(size_t)slist[i] * HH + tid * 4]);
        acc[0] += av * v.x; acc[1] += av * v.y;
        acc[2] += av * v.z; acc[3] += av * v.w;
    }
    *reinterpret_cast<f32x4*>(&partial[((size_t)(b * CH + ch)) * HH + tid * 4]) = acc;
}

// ============ K4b: out[b,h] = sum_ch partial[b,ch,h] ========================
__global__ __launch_bounds__(256) void k4b_reduce(const float* __restrict__ partial,
                                                  float* __restrict__ out) {
    int i = blockIdx.x * 256 + threadIdx.x;   // 0..32767
    int b = i >> 10, h = i & (HH - 1);
    float s = 0.f;
#pragma unroll
    for (int ch = 0; ch < CH; ++ch)
        s += partial[((size_t)(b * CH + ch)) * HH + h];
    out[i] = s;
}

extern "C" void kernel_launch(void* const* d_in, const int* in_sizes, int n_in,
                              void* d_out, int out_size, void* d_ws, size_t ws_size,
                              hipStream_t stream) {
    const float* h_i  = (const float*)d_in[0];
    const float* h_t  = (const float*)d_in[1];
    const int*   mask = (const int*)d_in[2];
    const float* W    = (const float*)d_in[3];
    const float* bias = (const float*)d_in[4];
    const float* u    = (const float*)d_in[5];
    float* out = (float*)d_out;

    float* c        = (float*)d_ws;                       // 8192
    float* y        = c + BB * AA;                        // 65536
    float* alpha    = y + BB * SS;                        // 65536
    float* partial  = alpha + BB * SS;                    // B*64*H = 2097152
    _Float16* W16   = (_Float16*)(partial + BB * CH * HH);  // 262144 f16
    int* sList      = (int*)(W16 + AA * HH);              // 65536
    int* cntb       = sList + BB * SS;                    // 32
    int* pcnt       = cntb + BB;                          // 65536

    k_prep<<<3104, 256, 0, stream>>>(W, h_t, bias, mask, W16, c, sList, cntb, pcnt);
    k2_mfma<<<512, 256, 0, stream>>>(h_i, W16, c, u, sList, cntb, y);
    k3_softmax<<<BB, 256, 0, stream>>>(y, mask, pcnt, alpha);
    k4a_partial<<<BB * CH, 256, 0, stream>>>(h_i, alpha, partial);
    k4b_reduce<<<(BB * HH) / 256, 256, 0, stream>>>(partial, out);
}

// Round 10
// 120.899 us; speedup vs baseline: 5.3810x; 1.2690x over previous
//
#include <hip/hip_runtime.h>
#include <math.h>

#define BB 32
#define SS 2048
#define HH 1024
#define AA 256
#define NEGV (-1e20f)
#define BK 32
#define CH 64
#define SCH (SS / CH)   // 32

typedef _Float16 half8 __attribute__((ext_vector_type(8)));
typedef float f32x4 __attribute__((ext_vector_type(4)));

__device__ inline void async_lds16(const void* g, void* l) {
    __builtin_amdgcn_global_load_lds(
        (const __attribute__((address_space(1))) unsigned int*)g,
        (__attribute__((address_space(3))) unsigned int*)l, 16, 0, 0);
}

// ============ PREP ==========================================================
// blocks [0,128):    W1 -> f16, K-major 16KB tiles (tile kt: unit = col*4+ks)
// blocks [128,2176): c[b,a] = bias[a] + h_t[b,:].W[a,H:2H]
// blocks [2176,2208): per-b compact list {s: count[s]>b} (pad 64) + pcnt
__global__ __launch_bounds__(256) void k_prep(const float* __restrict__ W,
                                              const float* __restrict__ h_t,
                                              const float* __restrict__ bias,
                                              const int* __restrict__ mask,
                                              _Float16* __restrict__ W16t,
                                              float* __restrict__ c,
                                              int* __restrict__ sList,
                                              int* __restrict__ cntb,
                                              int* __restrict__ pcnt) {
    const int blk = blockIdx.x;
    const int tid = threadIdx.x;
    __shared__ int lcnt;

    if (blk < 128) {                        // ---- role A: W16 tiled cast
        int idx = blk * 256 + tid;          // unit id, < 32768
        int kt = idx >> 10;
        int u  = idx & 1023;
        int col = u >> 2, ks = u & 3;
        const float* src = W + (size_t)col * 2 * HH + kt * BK + ks * 8;
        float4 a0 = *(const float4*)src;
        float4 a1 = *(const float4*)(src + 4);
        half8 h;
        h[0] = (_Float16)a0.x; h[1] = (_Float16)a0.y;
        h[2] = (_Float16)a0.z; h[3] = (_Float16)a0.w;
        h[4] = (_Float16)a1.x; h[5] = (_Float16)a1.y;
        h[6] = (_Float16)a1.z; h[7] = (_Float16)a1.w;
        *reinterpret_cast<half8*>(W16t + (size_t)idx * 8) = h;
        return;
    }
    if (blk < 2176) {                       // ---- role B: ctx GEMV
        int wave = tid >> 6;
        int lane = tid & 63;
        int pair = (blk - 128) * 4 + wave;  // < B*A = 8192
        int b = pair >> 8;
        int a = pair & (AA - 1);
        const float* ht = h_t + (size_t)b * HH;
        const float* w2 = W + (size_t)a * 2 * HH + HH;
        float acc = 0.f;
        for (int k = lane; k < HH; k += 64)
            acc += ht[k] * w2[k];
        for (int off = 32; off; off >>= 1)
            acc += __shfl_down(acc, off, 64);
        if (lane == 0) c[pair] = acc + bias[a];
        return;
    }
    // ---- role C: compaction + prefix counts
    const int b = blk - 2176;
    if (tid == 0) lcnt = 0;
    __syncthreads();
    int* lst = sList + b * SS;
#pragma unroll
    for (int i = 0; i < 8; ++i) {
        int s = tid + i * 256;
        int pref = 0, tot = 0;
#pragma unroll
        for (int bb = 0; bb < BB; ++bb) {
            int mv = (mask[bb * SS + s] != 0);
            tot += mv;
            if (bb <= b) pref += mv;
        }
        pcnt[b * SS + s] = pref;
        if (tot > b) { int p = atomicAdd(&lcnt, 1); lst[p] = s; }
    }
    __syncthreads();
    const int m = lcnt;
    if (tid == 0) cntb[b] = m;
    if (m > 0) {
        int padded = (m + 63) & ~63;
        int first = lst[0];
        for (int j = m + tid; j < padded; j += 256) lst[j] = first;
    }
}

// ============ K2: MFMA f16 score GEMM, 64x256 tile, ~544 active blocks ======
__global__ __launch_bounds__(256, 2) void k2_mfma(const float* __restrict__ h_i,
                                                  const _Float16* __restrict__ W16t,
                                                  const float* __restrict__ c,
                                                  const float* __restrict__ u,
                                                  const int* __restrict__ sList,
                                                  const int* __restrict__ cntb,
                                                  float* __restrict__ y) {
    __shared__ _Float16 Alds[2][4][64][8];    // 8 KB
    __shared__ _Float16 Blds[2][1024][8];     // 32 KB, unit = col*4+ks
    __shared__ float c_s[AA], u_s[AA];
    __shared__ float red[2][64];
    __shared__ int s_idx[64];

    const int t = blockIdx.x;
    int b = -1, ti = 0, base = 0;
    for (int bb = 0; bb < BB; ++bb) {
        int nt = (cntb[bb] + 63) >> 6;
        if (b < 0 && t < base + nt) { b = bb; ti = t - base; }
        base += nt;
    }
    if (b < 0) return;

    const int tid = threadIdx.x;
    const int lane = tid & 63;
    const int wave = tid >> 6;
    const int wr = wave >> 1;               // 0..1 -> 32-row slab
    const int wc = wave & 1;                // 0..1 -> 128-col slab

    if (tid < 64) s_idx[tid] = sList[b * SS + ti * 64 + tid];
    c_s[tid] = c[b * AA + tid];
    u_s[tid] = u[tid];
    __syncthreads();

    f32x4 acc[2][8];
#pragma unroll
    for (int rf = 0; rf < 2; ++rf)
#pragma unroll
        for (int cf = 0; cf < 8; ++cf) acc[rf][cf] = (f32x4){0.f, 0.f, 0.f, 0.f};

    const int arow = tid >> 2;              // 0..63
    const int aks = tid & 3;                // 0..3
    const float* Abase = h_i + ((size_t)b * SS + s_idx[arow]) * HH + aks * 8;

    const int sb0 = __builtin_amdgcn_readfirstlane(wave * 256);
    _Float16* Bflat = &Blds[0][0][0];       // one buffer = 8192 halfs (16 KB)

    const int kq = lane >> 4;
    const int lr = lane & 15;

    // ---- prologue: stage K-tile 0 into buffer 0 (coalesced: tiled W16t)
    {
#pragma unroll
        for (int i = 0; i < 4; ++i) {
            int sbase = sb0 + i * 64;
            async_lds16(W16t + (size_t)(sbase + lane) * 8,
                        Bflat + (size_t)sbase * 8);
        }
        float4 v0 = *(const float4*)Abase;
        float4 v1 = *(const float4*)(Abase + 4);
        half8 h;
        h[0] = (_Float16)v0.x; h[1] = (_Float16)v0.y;
        h[2] = (_Float16)v0.z; h[3] = (_Float16)v0.w;
        h[4] = (_Float16)v1.x; h[5] = (_Float16)v1.y;
        h[6] = (_Float16)v1.z; h[7] = (_Float16)v1.w;
        *reinterpret_cast<half8*>(&Alds[0][aks][arow][0]) = h;
    }
    __syncthreads();

    for (int t2 = 0; t2 < HH / BK; ++t2) {
        const int cur = t2 & 1, nxt = cur ^ 1;
        const int k1 = (t2 + 1) * BK;
        float4 v0, v1;
        if (t2 < HH / BK - 1) {
            // issue next B (async->LDS, 1KB contiguous per wave instr) + next A
#pragma unroll
            for (int i = 0; i < 4; ++i) {
                int sbase = sb0 + i * 64;
                async_lds16(W16t + (size_t)(t2 + 1) * 8192 + (size_t)(sbase + lane) * 8,
                            Bflat + (size_t)nxt * 8192 + (size_t)sbase * 8);
            }
            v0 = *(const float4*)(Abase + k1);
            v1 = *(const float4*)(Abase + k1 + 4);
        }

        half8 af[2], bf[8];
#pragma unroll
        for (int rf = 0; rf < 2; ++rf)
            af[rf] = *reinterpret_cast<half8*>(&Alds[cur][kq][wr * 32 + rf * 16 + lr][0]);
#pragma unroll
        for (int cf = 0; cf < 8; ++cf) {
            int col = wc * 128 + cf * 16 + lr;
            bf[cf] = *reinterpret_cast<half8*>(
                Bflat + (size_t)cur * 8192 + (size_t)(col * 4 + kq) * 8);
        }
#pragma unroll
        for (int rf = 0; rf < 2; ++rf)
#pragma unroll
            for (int cf = 0; cf < 8; ++cf)
                acc[rf][cf] = __builtin_amdgcn_mfma_f32_16x16x32_f16(
                    af[rf], bf[cf], acc[rf][cf], 0, 0, 0);

        if (t2 < HH / BK - 1) {
            half8 h;
            h[0] = (_Float16)v0.x; h[1] = (_Float16)v0.y;
            h[2] = (_Float16)v0.z; h[3] = (_Float16)v0.w;
            h[4] = (_Float16)v1.x; h[5] = (_Float16)v1.y;
            h[6] = (_Float16)v1.z; h[7] = (_Float16)v1.w;
            *reinterpret_cast<half8*>(&Alds[nxt][aks][arow][0]) = h;
        }
        __syncthreads();
    }

    // ---- epilogue: z += c[a]; y-row = sum_a tanh(z)*u[a]
#pragma unroll
    for (int rf = 0; rf < 2; ++rf) {
#pragma unroll
        for (int j = 0; j < 4; ++j) {
            float v = 0.f;
#pragma unroll
            for (int cf = 0; cf < 8; ++cf) {
                int col = wc * 128 + cf * 16 + lr;
                float z = acc[rf][cf][j] + c_s[col];
                v += tanhf(z) * u_s[col];
            }
            v += __shfl_xor(v, 1, 64);
            v += __shfl_xor(v, 2, 64);
            v += __shfl_xor(v, 4, 64);
            v += __shfl_xor(v, 8, 64);
            if (lr == 0) red[wc][wr * 32 + rf * 16 + kq * 4 + j] = v;
        }
    }
    __syncthreads();
    if (tid < 64) y[(size_t)b * SS + s_idx[tid]] = red[0][tid] + red[1][tid];
}

// ============ K34: fused row softmax stats + weighted chunk sum =============
__global__ __launch_bounds__(256) void k34(const float* __restrict__ h_i,
                                           const float* __restrict__ y,
                                           const int* __restrict__ mask,
                                           const int* __restrict__ pcnt,
                                           float* __restrict__ partial) {
    const int blk = blockIdx.x;
    const int b = blk >> 6;
    const int ch = blk & (CH - 1);
    const int tid = threadIdx.x;
    const int lane = tid & 63;
    const int wave = tid >> 6;
    __shared__ float rmax[4], rsum[4];
    __shared__ float aval[SCH];
    __shared__ int slist[SCH];
    __shared__ int mcnt;

    // row stats (recomputed per block; y/pcnt/mask rows are L2-resident)
    float beta[8];
    float mx = -INFINITY;
#pragma unroll
    for (int i = 0; i < 8; ++i) {
        int s = tid + i * 256;
        int p = pcnt[b * SS + s] - 1; if (p < 0) p = 0;
        float v = (mask[b * SS + s] != 0) ? y[(size_t)p * SS + s] : NEGV;
        beta[i] = v;
        mx = fmaxf(mx, v);
    }
    for (int off = 32; off; off >>= 1) mx = fmaxf(mx, __shfl_xor(mx, off, 64));
    if (lane == 0) rmax[wave] = mx;
    __syncthreads();
    mx = fmaxf(fmaxf(rmax[0], rmax[1]), fmaxf(rmax[2], rmax[3]));
    float sum = 0.f;
#pragma unroll
    for (int i = 0; i < 8; ++i) sum += expf(beta[i] - mx);
    for (int off = 32; off; off >>= 1) sum += __shfl_xor(sum, off, 64);
    if (lane == 0) rsum[wave] = sum;
    __syncthreads();
    sum = rsum[0] + rsum[1] + rsum[2] + rsum[3];
    const float inv = 1.f / sum;

    // this chunk's alphas + ballot compaction (skip alpha==0)
    float a = 0.f;
    bool nz = false;
    if (tid < SCH) {
        int s = ch * SCH + tid;
        if (mask[b * SS + s] != 0) {
            int p = pcnt[b * SS + s] - 1; if (p < 0) p = 0;
            a = expf(y[(size_t)p * SS + s] - mx) * inv;
            nz = (a != 0.f);
        }
    }
    unsigned long long mk = __ballot(nz);    // tid<32 all in wave 0
    if (tid < SCH) {
        int off = __popcll(mk & ((1ull << tid) - 1));
        if (nz) { slist[off] = tid; aval[off] = a; }
        if (tid == 0) mcnt = __popcll(mk);
    }
    __syncthreads();
    const int m = mcnt;
    const float* basep = h_i + (size_t)b * SS * HH + (size_t)ch * SCH * HH;
    f32x4 acc4 = {0.f, 0.f, 0.f, 0.f};
    for (int i2 = 0; i2 < m; ++i2) {
        float av = aval[i2];
        float4 v = *reinterpret_cast<const float4*>(
            &basep[(size_t)slist[i2] * HH + tid * 4]);
        acc4[0] += av * v.x; acc4[1] += av * v.y;
        acc4[2] += av * v.z; acc4[3] += av * v.w;
    }
    *reinterpret_cast<f32x4*>(&partial[(size_t)blk * HH + tid * 4]) = acc4;
}

// ============ K4b: out[b,h] = sum_ch partial[b,ch,h] ========================
__global__ __launch_bounds__(256) void k4b_reduce(const float* __restrict__ partial,
                                                  float* __restrict__ out) {
    int i = blockIdx.x * 256 + threadIdx.x;   // 0..32767
    int b = i >> 10, h = i & (HH - 1);
    float s = 0.f;
#pragma unroll
    for (int ch = 0; ch < CH; ++ch)
        s += partial[((size_t)(b * CH + ch)) * HH + h];
    out[i] = s;
}

extern "C" void kernel_launch(void* const* d_in, const int* in_sizes, int n_in,
                              void* d_out, int out_size, void* d_ws, size_t ws_size,
                              hipStream_t stream) {
    const float* h_i  = (const float*)d_in[0];
    const float* h_t  = (const float*)d_in[1];
    const int*   mask = (const int*)d_in[2];
    const float* W    = (const float*)d_in[3];
    const float* bias = (const float*)d_in[4];
    const float* u    = (const float*)d_in[5];
    float* out = (float*)d_out;

    float* c        = (float*)d_ws;                        // 8192
    float* y        = c + BB * AA;                         // 65536
    float* partial  = y + BB * SS;                         // B*CH*H = 2097152
    _Float16* W16t  = (_Float16*)(partial + BB * CH * HH); // 262144 f16
    int* sList      = (int*)(W16t + AA * HH);              // 65536
    int* cntb       = sList + BB * SS;                     // 32
    int* pcnt       = cntb + BB;                           // 65536

    k_prep<<<2208, 256, 0, stream>>>(W, h_t, bias, mask, W16t, c, sList, cntb, pcnt);
    k2_mfma<<<1024, 256, 0, stream>>>(h_i, W16t, c, u, sList, cntb, y);
    k34<<<BB * CH, 256, 0, stream>>>(h_i, y, mask, pcnt, partial);
    k4b_reduce<<<(BB * HH) / 256, 256, 0, stream>>>(partial, out);
}